// Round 3
// baseline (1392.528 us; speedup 1.0000x reference)
//
#include <hip/hip_runtime.h>
#include <stdint.h>

typedef __attribute__((ext_vector_type(8))) short bf16x8;
typedef __attribute__((ext_vector_type(4))) float f32x4;

static __device__ __forceinline__ unsigned short f2bf(float f){
  unsigned int u = __float_as_uint(f);
  return (unsigned short)((u + 0x7fffu + ((u >> 16) & 1u)) >> 16);
}

static __device__ __forceinline__ void gld_lds16(const void* g, void* l){
  __builtin_amdgcn_global_load_lds((__attribute__((address_space(1))) void*)(void*)g,
                                   (__attribute__((address_space(3))) void*)l, 16, 0, 0);
}

// ---------------- fp32 -> bf16 conversions ----------------
__global__ void k_f2bf(const float* __restrict__ in, unsigned short* __restrict__ out, int n){
  int i = (blockIdx.x * 256 + threadIdx.x) * 8;
  if (i + 8 <= n){
    float4 a = *(const float4*)(in + i);
    float4 b = *(const float4*)(in + i + 4);
    ushort4 r0 = { f2bf(a.x), f2bf(a.y), f2bf(a.z), f2bf(a.w) };
    ushort4 r1 = { f2bf(b.x), f2bf(b.y), f2bf(b.z), f2bf(b.w) };
    *(ushort4*)(out + i) = r0;
    *(ushort4*)(out + i + 4) = r1;
  } else {
    for (int j = i; j < n; ++j) out[j] = f2bf(in[j]);
  }
}

// pad fc2_w (40x256) into 48x256 bf16, zero rows >= 40
__global__ void k_w2pad(const float* __restrict__ w2, unsigned short* __restrict__ out){
  int e = blockIdx.x * 256 + threadIdx.x;
  int r = e >> 8, c = e & 255;
  float v = (r < 40) ? w2[r * 256 + c] : 0.f;
  out[e] = f2bf(v);
}

// ---------------- GEMM1: H = relu(X @ W1^T + b1), bf16 in, bf16 out ----------------
__global__ __launch_bounds__(256) void k_gemm1(
    const unsigned short* __restrict__ A,   // M x 512 bf16
    const unsigned short* __restrict__ B,   // 256 x 512 bf16
    const float* __restrict__ bias,         // 256 fp32
    unsigned short* __restrict__ H,         // M x 256 bf16
    int M)
{
  __shared__ __align__(16) unsigned short lA[128 * 32];
  __shared__ __align__(16) unsigned short lB[128 * 32];
  const int K = 512;
  int tid = threadIdx.x;
  int wave = tid >> 6, lane = tid & 63;
  int quad = lane >> 4, l16 = lane & 15;
  int rowBase = blockIdx.x * 128;
  int colBase = blockIdx.y * 128;
  int wm = (wave & 1) * 64, wn = (wave >> 1) * 64;

  f32x4 acc[4][4] = {};

  for (int k0 = 0; k0 < K; k0 += 32){
#pragma unroll
    for (int i = 0; i < 2; ++i){
      int issue = wave * 2 + i;
      int s = issue * 64 + lane;
      int r = s >> 2;
      int c = (s & 3) ^ (r & 3);
      int gr = rowBase + r; if (gr >= M) gr = M - 1;
      gld_lds16(A + (size_t)gr * K + k0 + c * 8, (char*)lA + issue * 1024);
      gld_lds16(B + (size_t)(colBase + r) * K + k0 + c * 8, (char*)lB + issue * 1024);
    }
    __syncthreads();
    bf16x8 af[4], bf[4];
#pragma unroll
    for (int mt = 0; mt < 4; ++mt){
      int r = wm + mt * 16 + l16;
      af[mt] = *(const bf16x8*)&lA[r * 32 + ((quad ^ (r & 3)) * 8)];
    }
#pragma unroll
    for (int nt = 0; nt < 4; ++nt){
      int r = wn + nt * 16 + l16;
      bf[nt] = *(const bf16x8*)&lB[r * 32 + ((quad ^ (r & 3)) * 8)];
    }
#pragma unroll
    for (int mt = 0; mt < 4; ++mt)
#pragma unroll
      for (int nt = 0; nt < 4; ++nt)
        acc[mt][nt] = __builtin_amdgcn_mfma_f32_16x16x32_bf16(af[mt], bf[nt], acc[mt][nt], 0, 0, 0);
    __syncthreads();
  }

#pragma unroll
  for (int nt = 0; nt < 4; ++nt){
    int col = colBase + wn + nt * 16 + l16;
    float bb = bias[col];
#pragma unroll
    for (int mt = 0; mt < 4; ++mt){
#pragma unroll
      for (int rr = 0; rr < 4; ++rr){
        int row = rowBase + wm + mt * 16 + quad * 4 + rr;
        if (row < M){
          float v = acc[mt][nt][rr] + bb;
          v = v > 0.f ? v : 0.f;
          H[(size_t)row * 256 + col] = f2bf(v);
        }
      }
    }
  }
}

// ---------------- GEMM2: FT = H @ W2^T + b2 (fp32 out) ----------------
__global__ __launch_bounds__(256) void k_gemm2(
    const unsigned short* __restrict__ H,
    const unsigned short* __restrict__ W2p,
    const float* __restrict__ b2,
    float* __restrict__ ft,
    int M)
{
  __shared__ __align__(16) unsigned short lW[48 * 264];
  int tid = threadIdx.x;
  int wave = tid >> 6, lane = tid & 63;
  int quad = lane >> 4, l16 = lane & 15;

  for (int idx = tid; idx < 48 * 32; idx += 256){
    int r = idx >> 5, c = idx & 31;
    *(bf16x8*)&lW[r * 264 + c * 8] = *(const bf16x8*)&W2p[r * 256 + c * 8];
  }
  __syncthreads();

  int row0 = blockIdx.x * 64 + wave * 16;
  f32x4 acc[3] = {};
  int r = row0 + l16; if (r >= M) r = M - 1;
#pragma unroll
  for (int ks = 0; ks < 8; ++ks){
    bf16x8 af = *(const bf16x8*)&H[(size_t)r * 256 + ks * 32 + quad * 8];
#pragma unroll
    for (int nt = 0; nt < 3; ++nt){
      bf16x8 bf = *(const bf16x8*)&lW[(nt * 16 + l16) * 264 + ks * 32 + quad * 8];
      acc[nt] = __builtin_amdgcn_mfma_f32_16x16x32_bf16(af, bf, acc[nt], 0, 0, 0);
    }
  }
#pragma unroll
  for (int nt = 0; nt < 3; ++nt){
    int col = nt * 16 + l16;
    if (col < 40){
      float bb = b2[col];
#pragma unroll
      for (int rr = 0; rr < 4; ++rr){
        int row = row0 + quad * 4 + rr;
        if (row < M) ft[(size_t)row * 40 + col] = acc[nt][rr] + bb;
      }
    }
  }
}

// ---------------- graph prep ----------------
__global__ void k_init0(int* __restrict__ deg, int* __restrict__ cnt,
                        const int* __restrict__ mask, int n){
  int i = blockIdx.x * 256 + threadIdx.x;
  if (i < n){ deg[i] = 1; cnt[i] = mask[i] ? 0 : 1; }
}

// 4 edges/thread; deg always, cnt only for unmasked cols
__global__ void k_count(const int* __restrict__ ei, int E, const int* __restrict__ mask,
                        int* __restrict__ deg, int* __restrict__ cnt){
  int e0 = (blockIdx.x * 256 + threadIdx.x) * 4;
  if (e0 + 4 <= E){
    int4 r4 = *(const int4*)(ei + e0);
    int4 c4 = *(const int4*)(ei + E + e0);
    atomicAdd(&deg[r4.x], 1); atomicAdd(&deg[r4.y], 1);
    atomicAdd(&deg[r4.z], 1); atomicAdd(&deg[r4.w], 1);
    if (!mask[c4.x]) atomicAdd(&cnt[c4.x], 1);
    if (!mask[c4.y]) atomicAdd(&cnt[c4.y], 1);
    if (!mask[c4.z]) atomicAdd(&cnt[c4.z], 1);
    if (!mask[c4.w]) atomicAdd(&cnt[c4.w], 1);
  } else {
    for (int e = e0; e < E; ++e){
      atomicAdd(&deg[ei[e]], 1);
      int c = ei[E + e];
      if (!mask[c]) atomicAdd(&cnt[c], 1);
    }
  }
}

__global__ void k_dis(const int* __restrict__ deg, float* __restrict__ dis,
                      float* __restrict__ dis2, int n){
  int i = blockIdx.x * 256 + threadIdx.x;
  if (i < n){
    float d = rsqrtf((float)deg[i]);
    dis[i] = d; dis2[i] = d * d;
  }
}

// exclusive scan over counts: per-1024-elem blocks
__global__ void k_scan1(const int* __restrict__ cnt, int* __restrict__ out, int* __restrict__ bsum, int n){
  __shared__ int ts[256];
  int tid = threadIdx.x;
  int base = blockIdx.x * 1024 + tid * 4;
  int v0 = (base     < n) ? cnt[base]     : 0;
  int v1 = (base + 1 < n) ? cnt[base + 1] : 0;
  int v2 = (base + 2 < n) ? cnt[base + 2] : 0;
  int v3 = (base + 3 < n) ? cnt[base + 3] : 0;
  int tot = v0 + v1 + v2 + v3;
  ts[tid] = tot; __syncthreads();
  int val = tot;
  for (int d = 1; d < 256; d <<= 1){
    int t = (tid >= d) ? ts[tid - d] : 0;
    __syncthreads();
    val += t; ts[tid] = val;
    __syncthreads();
  }
  int ex = val - tot;
  if (base     < n) out[base]     = ex;
  if (base + 1 < n) out[base + 1] = ex + v0;
  if (base + 2 < n) out[base + 2] = ex + v0 + v1;
  if (base + 3 < n) out[base + 3] = ex + v0 + v1 + v2;
  if (tid == 255) bsum[blockIdx.x] = val;
}
__global__ void k_scan2(int* __restrict__ bsum, int nb, int* __restrict__ offN){
  __shared__ int ts[256];
  int tid = threadIdx.x;
  int v = (tid < nb) ? bsum[tid] : 0;
  ts[tid] = v; __syncthreads();
  int val = v;
  for (int d = 1; d < 256; d <<= 1){
    int t = (tid >= d) ? ts[tid - d] : 0;
    __syncthreads();
    val += t; ts[tid] = val;
    __syncthreads();
  }
  if (tid < nb) bsum[tid] = val - v;
  if (tid == 255) *offN = val;
}
// finalize offsets; write self-loop entry (byte offset) and init cur = offs+1 for unmasked
__global__ void k_scan3(int* __restrict__ off, const int* __restrict__ bsum, int* __restrict__ cur,
                        const int* __restrict__ mask, int* __restrict__ srcO, int n){
  int base = blockIdx.x * 1024 + threadIdx.x * 4;
  int add = bsum[blockIdx.x];
#pragma unroll
  for (int i = 0; i < 4; ++i){
    int j = base + i;
    if (j < n){
      int v = off[j] + add; off[j] = v;
      if (!mask[j]){ srcO[v] = j * 80; cur[j] = v + 1; }
      else cur[j] = v;
    }
  }
}

// scatter edges into CSC (unmasked cols only); payload = src BYTE offset (src*80)
__global__ void k_scatter_e(const int* __restrict__ ei, int E, const int* __restrict__ mask,
                            int* __restrict__ cur, int* __restrict__ srcO){
  int e0 = (blockIdx.x * 256 + threadIdx.x) * 4;
  if (e0 + 4 <= E){
    int4 r4 = *(const int4*)(ei + e0);
    int4 c4 = *(const int4*)(ei + E + e0);
    if (!mask[c4.x]){ int p = atomicAdd(&cur[c4.x], 1); srcO[p] = r4.x * 80; }
    if (!mask[c4.y]){ int p = atomicAdd(&cur[c4.y], 1); srcO[p] = r4.y * 80; }
    if (!mask[c4.z]){ int p = atomicAdd(&cur[c4.z], 1); srcO[p] = r4.z * 80; }
    if (!mask[c4.w]){ int p = atomicAdd(&cur[c4.w], 1); srcO[p] = r4.w * 80; }
  } else {
    for (int e = e0; e < E; ++e){
      int c = ei[E + e];
      if (!mask[c]){ int p = atomicAdd(&cur[c], 1); srcO[p] = ei[e] * 80; }
    }
  }
}

// scaled-label init (packed u32 = 2 bf16 channels per word, 20 words/node)
__global__ void k_init_ps(const float* __restrict__ linit, const float* __restrict__ hard,
                          const float* __restrict__ dis, const int* __restrict__ mask,
                          unsigned* __restrict__ psI, unsigned* __restrict__ psA,
                          unsigned* __restrict__ psB, int nWords){
  int w = blockIdx.x * 256 + threadIdx.x;
  if (w >= nWords) return;
  int node = w / 20, l = w % 20;
  float d = dis[node];
  float2 li = *(const float2*)(linit + (size_t)node * 40 + 2 * l);
  unsigned lo = f2bf(li.x * d), hi = f2bf(li.y * d);
  psI[w] = lo | (hi << 16);
  if (mask[node]){
    float2 hv = *(const float2*)(hard + (size_t)node * 40 + 2 * l);
    unsigned pk = (unsigned)f2bf(hv.x * d) | ((unsigned)f2bf(hv.y * d) << 16);
    psA[w] = pk; psB[w] = pk;
  }
}

// ---------------- label propagation ----------------
// one wave per node; lanes 0-19 process edge i (u32 = 2 bf16 ch), lanes 32-51 edge i+1;
// cross-half combine via shfl_xor(32). srcO holds byte offsets (src*80).
__global__ __launch_bounds__(256) void k_prop(
    const int* __restrict__ offs, const int* __restrict__ srcO,
    const int* __restrict__ mask, const float* __restrict__ dis2,
    const unsigned* __restrict__ pin, unsigned* __restrict__ pout, int n)
{
  int node = blockIdx.x * 4 + (threadIdx.x >> 6);
  if (node >= n) return;
  if (mask[node]) return;                       // masked rows pre-set in pout
  int lane = threadIdx.x & 63;
  int h = lane >> 5;                            // 0: edge i, 1: edge i+1
  int l = lane & 31;                            // channel-pair idx; active if < 20
  int s = offs[node], e = offs[node + 1];
  const char* pinB = (const char*)pin;
  int cb = l * 4;
  float a0 = 0.f, a1 = 0.f, a2 = 0.f, a3 = 0.f;
  if (l < 20){
    int i = s;
    for (; i + 4 <= e; i += 4){
      int o0 = srcO[i + h];
      int o1 = srcO[i + 2 + h];
      unsigned v0 = *(const unsigned*)(pinB + o0 + cb);
      unsigned v1 = *(const unsigned*)(pinB + o1 + cb);
      a0 += __uint_as_float(v0 << 16);
      a1 += __uint_as_float(v0 & 0xffff0000u);
      a2 += __uint_as_float(v1 << 16);
      a3 += __uint_as_float(v1 & 0xffff0000u);
    }
    for (; i + 2 <= e; i += 2){
      int o0 = srcO[i + h];
      unsigned v0 = *(const unsigned*)(pinB + o0 + cb);
      a0 += __uint_as_float(v0 << 16);
      a1 += __uint_as_float(v0 & 0xffff0000u);
    }
    if (i < e && h == 0){
      int o0 = srcO[i];
      unsigned v0 = *(const unsigned*)(pinB + o0 + cb);
      a0 += __uint_as_float(v0 << 16);
      a1 += __uint_as_float(v0 & 0xffff0000u);
    }
  }
  float accL = a0 + a2, accH = a1 + a3;
  accL += __shfl_xor(accL, 32, 64);
  accH += __shfl_xor(accH, 32, 64);
  if (h == 0 && l < 20){
    float d2 = dis2[node];
    unsigned lo = f2bf(d2 * accL), hi = f2bf(d2 * accH);
    pout[node * 20 + l] = lo | (hi << 16);
  }
}

// final step fused with sigmoid-gate combine; covers ALL nodes
__global__ __launch_bounds__(256) void k_prop_final(
    const int* __restrict__ offs, const int* __restrict__ srcO,
    const int* __restrict__ mask, const float* __restrict__ dis,
    const unsigned* __restrict__ pin, const float* __restrict__ hard,
    const float* __restrict__ alpha, const float* __restrict__ ft,
    float* __restrict__ outp, int n)
{
  int node = blockIdx.x * 4 + (threadIdx.x >> 6);
  if (node >= n) return;
  int lane = threadIdx.x & 63;
  int h = lane >> 5, l = lane & 31;
  int m = mask[node];
  float vL = 0.f, vH = 0.f;
  if (!m){
    int s = offs[node], e = offs[node + 1];
    const char* pinB = (const char*)pin;
    int cb = l * 4;
    float a0 = 0.f, a1 = 0.f, a2 = 0.f, a3 = 0.f;
    if (l < 20){
      int i = s;
      for (; i + 4 <= e; i += 4){
        int o0 = srcO[i + h];
        int o1 = srcO[i + 2 + h];
        unsigned v0 = *(const unsigned*)(pinB + o0 + cb);
        unsigned v1 = *(const unsigned*)(pinB + o1 + cb);
        a0 += __uint_as_float(v0 << 16);
        a1 += __uint_as_float(v0 & 0xffff0000u);
        a2 += __uint_as_float(v1 << 16);
        a3 += __uint_as_float(v1 & 0xffff0000u);
      }
      for (; i + 2 <= e; i += 2){
        int o0 = srcO[i + h];
        unsigned v0 = *(const unsigned*)(pinB + o0 + cb);
        a0 += __uint_as_float(v0 << 16);
        a1 += __uint_as_float(v0 & 0xffff0000u);
      }
      if (i < e && h == 0){
        int o0 = srcO[i];
        unsigned v0 = *(const unsigned*)(pinB + o0 + cb);
        a0 += __uint_as_float(v0 << 16);
        a1 += __uint_as_float(v0 & 0xffff0000u);
      }
    }
    float accL = a0 + a2, accH = a1 + a3;
    accL += __shfl_xor(accL, 32, 64);
    accH += __shfl_xor(accH, 32, 64);
    float d = dis[node];
    vL = d * accL; vH = d * accH;
  }
  if (h == 0 && l < 20){
    float a = 1.f / (1.f + __expf(-alpha[node]));
    float2 fv = *(const float2*)(ft + (size_t)node * 40 + 2 * l);
    if (m){
      float2 hv = *(const float2*)(hard + (size_t)node * 40 + 2 * l);
      vL = hv.x; vH = hv.y;
    }
    float2 o;
    o.x = a * vL + (1.f - a) * fv.x;
    o.y = a * vH + (1.f - a) * fv.y;
    *(float2*)(outp + (size_t)node * 40 + 2 * l) = o;
  }
}

extern "C" void kernel_launch(void* const* d_in, const int* in_sizes, int n_in,
                              void* d_out, int out_size, void* d_ws, size_t ws_size,
                              hipStream_t stream)
{
  const float* x     = (const float*)d_in[0];
  const int*   ei    = (const int*)d_in[1];
  const float* linit = (const float*)d_in[2];
  const int*   mask  = (const int*)d_in[3];
  const float* hard  = (const float*)d_in[4];
  const float* w1    = (const float*)d_in[5];
  const float* b1    = (const float*)d_in[6];
  const float* w2    = (const float*)d_in[7];
  const float* b2    = (const float*)d_in[8];
  const float* alpha = (const float*)d_in[9];
  float* out = (float*)d_out;

  const int N   = in_sizes[3];        // 100000
  const int E   = in_sizes[1] / 2;    // 3200000
  const int K1  = in_sizes[0] / N;    // 512
  const int HID = in_sizes[6];        // 256

  char* ws = (char*)d_ws;
  size_t sXB = (size_t)N * K1 * 2;    // x_bf16 region, reused for graph arrays
  size_t sH  = (size_t)N * HID * 2;   // h_bf16 region, reused for ps buffers

  unsigned short* xb  = (unsigned short*)(ws);
  unsigned short* hb  = (unsigned short*)(ws + sXB);
  unsigned short* w1b = (unsigned short*)(ws + sXB + sH);
  unsigned short* w2p = (unsigned short*)(ws + sXB + sH + (size_t)HID * K1 * 2);
  float*          ft  = (float*)(ws + sXB + sH + (size_t)HID * K1 * 2 + 48 * 256 * 2);

  // graph arrays alias xb region (used only after gemm1 consumed xb)
  char* g = ws;
  int*   srcO = (int*)g;                      g += (size_t)(E + N) * 4;
  int*   deg  = (int*)g;                      g += (size_t)N * 4;
  int*   cnt  = (int*)g;                      g += (size_t)N * 4;
  float* dis  = (float*)g;                    g += (size_t)N * 4;
  float* dis2 = (float*)g;                    g += (size_t)N * 4;
  int*   offs = (int*)g;                      g += (size_t)(N + 64) * 4;
  int*   cur  = (int*)g;                      g += (size_t)N * 4;
  int*   bsum = (int*)g;                      g += 1024;

  // ps buffers alias hb region (used only after gemm2 consumed hb)
  unsigned* psI = (unsigned*)(ws + sXB);
  unsigned* psA = (unsigned*)(ws + sXB + (size_t)N * 40 * 2);
  unsigned* psB = (unsigned*)(ws + sXB + (size_t)N * 40 * 4);

  // 1) conversions
  k_f2bf<<<(N * K1 / 8 + 255) / 256, 256, 0, stream>>>(x, xb, N * K1);
  k_f2bf<<<(HID * K1 / 8 + 255) / 256, 256, 0, stream>>>(w1, w1b, HID * K1);
  k_w2pad<<<48, 256, 0, stream>>>(w2, w2p);

  // 2) MLP branch
  dim3 g1((N + 127) / 128, HID / 128);
  k_gemm1<<<g1, 256, 0, stream>>>(xb, w1b, b1, hb, N);
  k_gemm2<<<(N + 63) / 64, 256, 0, stream>>>(hb, w2p, b2, ft, N);

  // 3) graph prep (CSC over unmasked cols only)
  k_init0<<<(N + 255) / 256, 256, 0, stream>>>(deg, cnt, mask, N);
  k_count<<<(E / 4 + 255) / 256, 256, 0, stream>>>(ei, E, mask, deg, cnt);
  k_dis<<<(N + 255) / 256, 256, 0, stream>>>(deg, dis, dis2, N);
  int nsb = (N + 1023) / 1024;
  k_scan1<<<nsb, 256, 0, stream>>>(cnt, offs, bsum, N);
  k_scan2<<<1, 256, 0, stream>>>(bsum, nsb, offs + N);
  k_scan3<<<nsb, 256, 0, stream>>>(offs, bsum, cur, mask, srcO, N);
  k_scatter_e<<<(E / 4 + 255) / 256, 256, 0, stream>>>(ei, E, mask, cur, srcO);

  // 4) scaled-label init + 9 prop steps + fused final
  k_init_ps<<<(N * 20 + 255) / 256, 256, 0, stream>>>(linit, hard, dis, mask, psI, psA, psB, N * 20);

  const unsigned* pin = psI;
  for (int s = 0; s < 9; ++s){
    unsigned* po = (s & 1) ? psB : psA;
    k_prop<<<(N + 3) / 4, 256, 0, stream>>>(offs, srcO, mask, dis2, pin, po, N);
    pin = po;
  }
  k_prop_final<<<(N + 3) / 4, 256, 0, stream>>>(offs, srcO, mask, dis, pin, hard, alpha, ft, out, N);
}

// Round 5
// 1069.127 us; speedup vs baseline: 1.3025x; 1.3025x over previous
//
#include <hip/hip_runtime.h>
#include <stdint.h>

typedef __attribute__((ext_vector_type(8))) short bf16x8;
typedef __attribute__((ext_vector_type(4))) float f32x4;

static __device__ __forceinline__ unsigned short f2bf(float f){
  unsigned int u = __float_as_uint(f);
  return (unsigned short)((u + 0x7fffu + ((u >> 16) & 1u)) >> 16);
}
static __device__ __forceinline__ float bf2f(unsigned short h){
  return __uint_as_float(((unsigned int)h) << 16);
}

static __device__ __forceinline__ void gld_lds16(const void* g, void* l){
  __builtin_amdgcn_global_load_lds((__attribute__((address_space(1))) void*)(void*)g,
                                   (__attribute__((address_space(3))) void*)l, 16, 0, 0);
}

// ---------------- fused: edge-count histogram + fp32->bf16 conversions ----------------
// blocks [0,CB): count; [CB,CB+XB): f2bf x; [CB+XB,CB+XB+W1B): f2bf w1; rest: w2pad.
// count is atomic-pipe bound (~0.4% VALU, 11% HBM); conversions are BW-bound -> overlap.
__global__ __launch_bounds__(256) void k_mega(
    const int* __restrict__ ei, int E, const int* __restrict__ mask,
    int* __restrict__ deg, int* __restrict__ cnt,
    const float* __restrict__ x, unsigned short* __restrict__ xb, int nx,
    const float* __restrict__ w1, unsigned short* __restrict__ w1b, int nw1,
    const float* __restrict__ w2, unsigned short* __restrict__ w2p,
    int CB, int XB, int W1B)
{
  int b = blockIdx.x;
  if (b < CB){
    int e0 = (b * 256 + threadIdx.x) * 4;
    if (e0 + 4 <= E){
      int4 r4 = *(const int4*)(ei + e0);
      int4 c4 = *(const int4*)(ei + E + e0);
      atomicAdd(&deg[r4.x], 1); atomicAdd(&deg[r4.y], 1);
      atomicAdd(&deg[r4.z], 1); atomicAdd(&deg[r4.w], 1);
      if (!mask[c4.x]) atomicAdd(&cnt[c4.x], 1);
      if (!mask[c4.y]) atomicAdd(&cnt[c4.y], 1);
      if (!mask[c4.z]) atomicAdd(&cnt[c4.z], 1);
      if (!mask[c4.w]) atomicAdd(&cnt[c4.w], 1);
    } else {
      for (int e = e0; e < E; ++e){
        atomicAdd(&deg[ei[e]], 1);
        int c = ei[E + e];
        if (!mask[c]) atomicAdd(&cnt[c], 1);
      }
    }
  } else if (b < CB + XB){
    int i = ((b - CB) * 256 + threadIdx.x) * 8;
    if (i + 8 <= nx){
      float4 a = *(const float4*)(x + i);
      float4 c = *(const float4*)(x + i + 4);
      ushort4 r0 = { f2bf(a.x), f2bf(a.y), f2bf(a.z), f2bf(a.w) };
      ushort4 r1 = { f2bf(c.x), f2bf(c.y), f2bf(c.z), f2bf(c.w) };
      *(ushort4*)(xb + i) = r0;
      *(ushort4*)(xb + i + 4) = r1;
    } else {
      for (int j = i; j < nx; ++j) xb[j] = f2bf(x[j]);
    }
  } else if (b < CB + XB + W1B){
    int i = ((b - CB - XB) * 256 + threadIdx.x) * 8;
    if (i + 8 <= nw1){
      float4 a = *(const float4*)(w1 + i);
      float4 c = *(const float4*)(w1 + i + 4);
      ushort4 r0 = { f2bf(a.x), f2bf(a.y), f2bf(a.z), f2bf(a.w) };
      ushort4 r1 = { f2bf(c.x), f2bf(c.y), f2bf(c.z), f2bf(c.w) };
      *(ushort4*)(w1b + i) = r0;
      *(ushort4*)(w1b + i + 4) = r1;
    } else {
      for (int j = i; j < nw1; ++j) w1b[j] = f2bf(w1[j]);
    }
  } else {
    int e = (b - CB - XB - W1B) * 256 + threadIdx.x;   // 48*256 elems
    int r = e >> 8, c = e & 255;
    float v = (r < 40) ? w2[r * 256 + c] : 0.f;
    w2p[e] = f2bf(v);
  }
}

// ---------------- GEMM1: H = relu(X @ W1^T + b1), bf16 in, bf16 out ----------------
__global__ __launch_bounds__(256) void k_gemm1(
    const unsigned short* __restrict__ A,   // M x 512 bf16
    const unsigned short* __restrict__ B,   // 256 x 512 bf16
    const float* __restrict__ bias,         // 256 fp32
    unsigned short* __restrict__ H,         // M x 256 bf16
    int M)
{
  __shared__ __align__(16) unsigned short lA[128 * 32];
  __shared__ __align__(16) unsigned short lB[128 * 32];
  const int K = 512;
  int tid = threadIdx.x;
  int wave = tid >> 6, lane = tid & 63;
  int quad = lane >> 4, l16 = lane & 15;
  int rowBase = blockIdx.x * 128;
  int colBase = blockIdx.y * 128;
  int wm = (wave & 1) * 64, wn = (wave >> 1) * 64;

  f32x4 acc[4][4] = {};

  for (int k0 = 0; k0 < K; k0 += 32){
#pragma unroll
    for (int i = 0; i < 2; ++i){
      int issue = wave * 2 + i;
      int s = issue * 64 + lane;
      int r = s >> 2;
      int c = (s & 3) ^ (r & 3);
      int gr = rowBase + r; if (gr >= M) gr = M - 1;
      gld_lds16(A + (size_t)gr * K + k0 + c * 8, (char*)lA + issue * 1024);
      gld_lds16(B + (size_t)(colBase + r) * K + k0 + c * 8, (char*)lB + issue * 1024);
    }
    __syncthreads();
    bf16x8 af[4], bf[4];
#pragma unroll
    for (int mt = 0; mt < 4; ++mt){
      int r = wm + mt * 16 + l16;
      af[mt] = *(const bf16x8*)&lA[r * 32 + ((quad ^ (r & 3)) * 8)];
    }
#pragma unroll
    for (int nt = 0; nt < 4; ++nt){
      int r = wn + nt * 16 + l16;
      bf[nt] = *(const bf16x8*)&lB[r * 32 + ((quad ^ (r & 3)) * 8)];
    }
#pragma unroll
    for (int mt = 0; mt < 4; ++mt)
#pragma unroll
      for (int nt = 0; nt < 4; ++nt)
        acc[mt][nt] = __builtin_amdgcn_mfma_f32_16x16x32_bf16(af[mt], bf[nt], acc[mt][nt], 0, 0, 0);
    __syncthreads();
  }

#pragma unroll
  for (int nt = 0; nt < 4; ++nt){
    int col = colBase + wn + nt * 16 + l16;
    float bb = bias[col];
#pragma unroll
    for (int mt = 0; mt < 4; ++mt){
#pragma unroll
      for (int rr = 0; rr < 4; ++rr){
        int row = rowBase + wm + mt * 16 + quad * 4 + rr;
        if (row < M){
          float v = acc[mt][nt][rr] + bb;
          v = v > 0.f ? v : 0.f;
          H[(size_t)row * 256 + col] = f2bf(v);
        }
      }
    }
  }
}

// ---------------- GEMM2: FT = H @ W2^T + b2 (fp32 out) ----------------
__global__ __launch_bounds__(256) void k_gemm2(
    const unsigned short* __restrict__ H,
    const unsigned short* __restrict__ W2p,
    const float* __restrict__ b2,
    float* __restrict__ ft,
    int M)
{
  __shared__ __align__(16) unsigned short lW[48 * 264];
  int tid = threadIdx.x;
  int wave = tid >> 6, lane = tid & 63;
  int quad = lane >> 4, l16 = lane & 15;

  for (int idx = tid; idx < 48 * 32; idx += 256){
    int r = idx >> 5, c = idx & 31;
    *(bf16x8*)&lW[r * 264 + c * 8] = *(const bf16x8*)&W2p[r * 256 + c * 8];
  }
  __syncthreads();

  int row0 = blockIdx.x * 64 + wave * 16;
  f32x4 acc[3] = {};
  int r = row0 + l16; if (r >= M) r = M - 1;
#pragma unroll
  for (int ks = 0; ks < 8; ++ks){
    bf16x8 af = *(const bf16x8*)&H[(size_t)r * 256 + ks * 32 + quad * 8];
#pragma unroll
    for (int nt = 0; nt < 3; ++nt){
      bf16x8 bf = *(const bf16x8*)&lW[(nt * 16 + l16) * 264 + ks * 32 + quad * 8];
      acc[nt] = __builtin_amdgcn_mfma_f32_16x16x32_bf16(af, bf, acc[nt], 0, 0, 0);
    }
  }
#pragma unroll
  for (int nt = 0; nt < 3; ++nt){
    int col = nt * 16 + l16;
    if (col < 40){
      float bb = b2[col];
#pragma unroll
      for (int rr = 0; rr < 4; ++rr){
        int row = row0 + quad * 4 + rr;
        if (row < M) ft[(size_t)row * 40 + col] = acc[nt][rr] + bb;
      }
    }
  }
}

// ---------------- graph prep ----------------
// deg holds RAW row-count (no self): dis = rsqrt(raw+1). Builds unmasked list.
__global__ void k_dis(const int* __restrict__ deg, const int* __restrict__ mask,
                      float* __restrict__ dis, float* __restrict__ dis2,
                      int* __restrict__ list, int* __restrict__ nUn, int n){
  int i = blockIdx.x * 256 + threadIdx.x;
  if (i < n){
    float d = rsqrtf((float)(deg[i] + 1));
    dis[i] = d; dis2[i] = d * d;
    if (!mask[i]){ int pos = atomicAdd(nUn, 1); list[pos] = i; }
  }
}

// exclusive scan over counts (cnt holds RAW in-count; +1 self for unmasked applied here)
__global__ void k_scan1(const int* __restrict__ cnt, const int* __restrict__ mask,
                        int* __restrict__ out, int* __restrict__ bsum, int n){
  __shared__ int ts[256];
  int tid = threadIdx.x;
  int base = blockIdx.x * 1024 + tid * 4;
  int v0 = (base     < n) ? cnt[base]     + (mask[base]     ? 0 : 1) : 0;
  int v1 = (base + 1 < n) ? cnt[base + 1] + (mask[base + 1] ? 0 : 1) : 0;
  int v2 = (base + 2 < n) ? cnt[base + 2] + (mask[base + 2] ? 0 : 1) : 0;
  int v3 = (base + 3 < n) ? cnt[base + 3] + (mask[base + 3] ? 0 : 1) : 0;
  int tot = v0 + v1 + v2 + v3;
  ts[tid] = tot; __syncthreads();
  int val = tot;
  for (int d = 1; d < 256; d <<= 1){
    int t = (tid >= d) ? ts[tid - d] : 0;
    __syncthreads();
    val += t; ts[tid] = val;
    __syncthreads();
  }
  int ex = val - tot;
  if (base     < n) out[base]     = ex;
  if (base + 1 < n) out[base + 1] = ex + v0;
  if (base + 2 < n) out[base + 2] = ex + v0 + v1;
  if (base + 3 < n) out[base + 3] = ex + v0 + v1 + v2;
  if (tid == 255) bsum[blockIdx.x] = val;
}
__global__ void k_scan2(int* __restrict__ bsum, int nb, int* __restrict__ offN){
  __shared__ int ts[256];
  int tid = threadIdx.x;
  int v = (tid < nb) ? bsum[tid] : 0;
  ts[tid] = v; __syncthreads();
  int val = v;
  for (int d = 1; d < 256; d <<= 1){
    int t = (tid >= d) ? ts[tid - d] : 0;
    __syncthreads();
    val += t; ts[tid] = val;
    __syncthreads();
  }
  if (tid < nb) bsum[tid] = val - v;
  if (tid == 255) *offN = val;
}
// finalize offsets; write self-loop entry and init cur = offs+1 for unmasked
__global__ void k_scan3(int* __restrict__ off, const int* __restrict__ bsum, int* __restrict__ cur,
                        const int* __restrict__ mask, int* __restrict__ srcA, int n){
  int base = blockIdx.x * 1024 + threadIdx.x * 4;
  int add = bsum[blockIdx.x];
#pragma unroll
  for (int i = 0; i < 4; ++i){
    int j = base + i;
    if (j < n){
      int v = off[j] + add; off[j] = v;
      if (!mask[j]){ srcA[v] = j; cur[j] = v + 1; }
      else cur[j] = v;
    }
  }
}

// scatter edges into CSC (unmasked cols only)
__global__ void k_scatter_e(const int* __restrict__ ei, int E, const int* __restrict__ mask,
                            int* __restrict__ cur, int* __restrict__ srcA){
  int e0 = (blockIdx.x * 256 + threadIdx.x) * 4;
  if (e0 + 4 <= E){
    int4 r4 = *(const int4*)(ei + e0);
    int4 c4 = *(const int4*)(ei + E + e0);
    if (!mask[c4.x]){ int p = atomicAdd(&cur[c4.x], 1); srcA[p] = r4.x; }
    if (!mask[c4.y]){ int p = atomicAdd(&cur[c4.y], 1); srcA[p] = r4.y; }
    if (!mask[c4.z]){ int p = atomicAdd(&cur[c4.z], 1); srcA[p] = r4.z; }
    if (!mask[c4.w]){ int p = atomicAdd(&cur[c4.w], 1); srcA[p] = r4.w; }
  } else {
    for (int e = e0; e < E; ++e){
      int c = ei[E + e];
      if (!mask[c]){ int p = atomicAdd(&cur[c], 1); srcA[p] = ei[e]; }
    }
  }
}

// scaled-label init (packed u32 = 2 bf16 channels per word, 20 words/node)
__global__ void k_init_ps(const float* __restrict__ linit, const float* __restrict__ hard,
                          const float* __restrict__ dis, const int* __restrict__ mask,
                          unsigned* __restrict__ psI, unsigned* __restrict__ psA,
                          unsigned* __restrict__ psB, int nWords){
  int w = blockIdx.x * 256 + threadIdx.x;
  if (w >= nWords) return;
  int node = w / 20, l = w % 20;
  float d = dis[node];
  float2 li = *(const float2*)(linit + (size_t)node * 40 + 2 * l);
  unsigned lo = f2bf(li.x * d), hi = f2bf(li.y * d);
  psI[w] = lo | (hi << 16);
  if (mask[node]){
    float2 hv = *(const float2*)(hard + (size_t)node * 40 + 2 * l);
    unsigned pk = (unsigned)f2bf(hv.x * d) | ((unsigned)f2bf(hv.y * d) << 16);
    psA[w] = pk; psB[w] = pk;
  }
}

// ---------------- label propagation (round-2 structure, 8-way unroll) ----------------
// ps_out[c] = dis2[c] * sum_{r in CSC(c)} ps_in[r]   (scaled labels, bf16)
__global__ __launch_bounds__(256) void k_prop(
    const int* __restrict__ offs, const int* __restrict__ srcA,
    const int* __restrict__ list, const int* __restrict__ nUn,
    const float* __restrict__ dis2,
    const unsigned short* __restrict__ pin, unsigned short* __restrict__ pout)
{
  int widx = blockIdx.x * 4 + (threadIdx.x >> 6);
  if (widx >= *nUn) return;
  int node = __builtin_amdgcn_readfirstlane(list[widx]);
  int lane = threadIdx.x & 63;
  if (lane >= 40) return;
  int s = offs[node], e = offs[node + 1];
  float a0 = 0.f, a1 = 0.f, a2 = 0.f, a3 = 0.f;
  int i = s;
  for (; i + 8 <= e; i += 8){
    int s0 = srcA[i],     s1 = srcA[i + 1], s2 = srcA[i + 2], s3 = srcA[i + 3];
    int s4 = srcA[i + 4], s5 = srcA[i + 5], s6 = srcA[i + 6], s7 = srcA[i + 7];
    a0 += bf2f(pin[s0 * 40 + lane]);
    a1 += bf2f(pin[s1 * 40 + lane]);
    a2 += bf2f(pin[s2 * 40 + lane]);
    a3 += bf2f(pin[s3 * 40 + lane]);
    a0 += bf2f(pin[s4 * 40 + lane]);
    a1 += bf2f(pin[s5 * 40 + lane]);
    a2 += bf2f(pin[s6 * 40 + lane]);
    a3 += bf2f(pin[s7 * 40 + lane]);
  }
  for (; i + 4 <= e; i += 4){
    int s0 = srcA[i], s1 = srcA[i + 1], s2 = srcA[i + 2], s3 = srcA[i + 3];
    a0 += bf2f(pin[s0 * 40 + lane]);
    a1 += bf2f(pin[s1 * 40 + lane]);
    a2 += bf2f(pin[s2 * 40 + lane]);
    a3 += bf2f(pin[s3 * 40 + lane]);
  }
  for (; i < e; ++i) a0 += bf2f(pin[srcA[i] * 40 + lane]);
  pout[node * 40 + lane] = f2bf(dis2[node] * ((a0 + a1) + (a2 + a3)));
}

// final step fused with sigmoid-gate combine; covers ALL nodes
__global__ __launch_bounds__(256) void k_prop_final(
    const int* __restrict__ offs, const int* __restrict__ srcA,
    const float* __restrict__ dis, const unsigned short* __restrict__ pin,
    const int* __restrict__ mask, const float* __restrict__ hard,
    const float* __restrict__ alpha, const float* __restrict__ ft,
    float* __restrict__ outp, int n)
{
  int node = blockIdx.x * 4 + (threadIdx.x >> 6);
  if (node >= n) return;
  node = __builtin_amdgcn_readfirstlane(node);
  int lane = threadIdx.x & 63;
  if (lane >= 40) return;
  float a = 1.f / (1.f + __expf(-alpha[node]));
  float v;
  if (mask[node]){
    v = hard[(size_t)node * 40 + lane];
  } else {
    int s = offs[node], e = offs[node + 1];
    float a0 = 0.f, a1 = 0.f, a2 = 0.f, a3 = 0.f;
    int i = s;
    for (; i + 8 <= e; i += 8){
      int s0 = srcA[i],     s1 = srcA[i + 1], s2 = srcA[i + 2], s3 = srcA[i + 3];
      int s4 = srcA[i + 4], s5 = srcA[i + 5], s6 = srcA[i + 6], s7 = srcA[i + 7];
      a0 += bf2f(pin[s0 * 40 + lane]);
      a1 += bf2f(pin[s1 * 40 + lane]);
      a2 += bf2f(pin[s2 * 40 + lane]);
      a3 += bf2f(pin[s3 * 40 + lane]);
      a0 += bf2f(pin[s4 * 40 + lane]);
      a1 += bf2f(pin[s5 * 40 + lane]);
      a2 += bf2f(pin[s6 * 40 + lane]);
      a3 += bf2f(pin[s7 * 40 + lane]);
    }
    for (; i + 4 <= e; i += 4){
      int s0 = srcA[i], s1 = srcA[i + 1], s2 = srcA[i + 2], s3 = srcA[i + 3];
      a0 += bf2f(pin[s0 * 40 + lane]);
      a1 += bf2f(pin[s1 * 40 + lane]);
      a2 += bf2f(pin[s2 * 40 + lane]);
      a3 += bf2f(pin[s3 * 40 + lane]);
    }
    for (; i < e; ++i) a0 += bf2f(pin[srcA[i] * 40 + lane]);
    v = dis[node] * ((a0 + a1) + (a2 + a3));
  }
  outp[(size_t)node * 40 + lane] = a * v + (1.f - a) * ft[(size_t)node * 40 + lane];
}

extern "C" void kernel_launch(void* const* d_in, const int* in_sizes, int n_in,
                              void* d_out, int out_size, void* d_ws, size_t ws_size,
                              hipStream_t stream)
{
  const float* x     = (const float*)d_in[0];
  const int*   ei    = (const int*)d_in[1];
  const float* linit = (const float*)d_in[2];
  const int*   mask  = (const int*)d_in[3];
  const float* hard  = (const float*)d_in[4];
  const float* w1    = (const float*)d_in[5];
  const float* b1    = (const float*)d_in[6];
  const float* w2    = (const float*)d_in[7];
  const float* b2    = (const float*)d_in[8];
  const float* alpha = (const float*)d_in[9];
  float* out = (float*)d_out;

  const int N   = in_sizes[3];        // 100000
  const int E   = in_sizes[1] / 2;    // 3200000
  const int K1  = in_sizes[0] / N;    // 512
  const int HID = in_sizes[6];        // 256

  char* ws = (char*)d_ws;
  size_t sXB = (size_t)N * K1 * 2;    // x_bf16 region, reused for graph arrays
  size_t sH  = (size_t)N * HID * 2;   // h_bf16 region, reused for ps buffers

  unsigned short* xb  = (unsigned short*)(ws);
  unsigned short* hb  = (unsigned short*)(ws + sXB);
  unsigned short* w1b = (unsigned short*)(ws + sXB + sH);
  unsigned short* w2p = (unsigned short*)(ws + sXB + sH + (size_t)HID * K1 * 2);
  float*          ft  = (float*)(ws + sXB + sH + (size_t)HID * K1 * 2 + 48 * 256 * 2);

  // deg/cnt live in the ft region ONLY until the scans consume them (before gemm2
  // overwrites ft). nUn must SURVIVE until the last prop -> lives in the xb-alias
  // chain below (this was the round-4 bug: nUn in ft got clobbered by gemm2).
  int* deg = (int*)ft;
  int* cnt = deg + N;

  // remaining graph arrays alias the xb region (touched only after gemm1 consumed xb)
  char* g = ws;
  int*   srcA = (int*)g;                      g += (size_t)(E + N) * 4;
  float* dis  = (float*)g;                    g += (size_t)N * 4;
  float* dis2 = (float*)g;                    g += (size_t)N * 4;
  int*   offs = (int*)g;                      g += (size_t)(N + 64) * 4;
  int*   cur  = (int*)g;                      g += (size_t)N * 4;
  int*   bsum = (int*)g;                      g += 1024;
  int*   list = (int*)g;                      g += (size_t)N * 4;
  int*   nUn  = (int*)g;                      g += 256;

  // ps buffers alias hb region (touched only after gemm2 consumed hb)
  unsigned* psI = (unsigned*)(ws + sXB);
  unsigned* psA = (unsigned*)(ws + sXB + (size_t)N * 40 * 2);
  unsigned* psB = (unsigned*)(ws + sXB + (size_t)N * 40 * 4);

  // 1) zero deg/cnt, then fused [count | f2bf(x) | f2bf(w1) | w2pad]
  hipMemsetAsync(deg, 0, (size_t)(2 * N) * 4, stream);
  int nx  = N * K1;
  int nw1 = HID * K1;
  int CB  = (E / 4 + 255) / 256;
  int XB  = (nx / 8 + 255) / 256;
  int W1B = (nw1 / 8 + 255) / 256;
  int W2B = 48;
  k_mega<<<CB + XB + W1B + W2B, 256, 0, stream>>>(ei, E, mask, deg, cnt,
                                                  x, xb, nx, w1, w1b, nw1, w2, w2p,
                                                  CB, XB, W1B);

  // 2) GEMM1 (consumes xb, w1b)
  dim3 g1((N + 127) / 128, HID / 128);
  k_gemm1<<<g1, 256, 0, stream>>>(xb, w1b, b1, hb, N);

  // 3) graph prep; nUn zeroed here (xb region is dead only after gemm1)
  hipMemsetAsync(nUn, 0, 4, stream);
  k_dis<<<(N + 255) / 256, 256, 0, stream>>>(deg, mask, dis, dis2, list, nUn, N);
  int nsb = (N + 1023) / 1024;
  k_scan1<<<nsb, 256, 0, stream>>>(cnt, mask, offs, bsum, N);
  k_scan2<<<1, 256, 0, stream>>>(bsum, nsb, offs + N);
  k_scan3<<<nsb, 256, 0, stream>>>(offs, bsum, cur, mask, srcA, N);

  // 4) GEMM2 (writes ft over dead deg/cnt)
  k_gemm2<<<(N + 63) / 64, 256, 0, stream>>>(hb, w2p, b2, ft, N);

  // 5) scatter + scaled-label init
  k_scatter_e<<<(E / 4 + 255) / 256, 256, 0, stream>>>(ei, E, mask, cur, srcA);
  k_init_ps<<<(N * 20 + 255) / 256, 256, 0, stream>>>(linit, hard, dis, mask, psI, psA, psB, N * 20);

  // 6) 9 prop steps + fused final
  const unsigned short* pin = (const unsigned short*)psI;
  for (int s = 0; s < 9; ++s){
    unsigned short* po = (unsigned short*)((s & 1) ? psB : psA);
    k_prop<<<(N + 3) / 4, 256, 0, stream>>>(offs, srcA, list, nUn, dis2, pin, po);
    pin = po;
  }
  k_prop_final<<<(N + 3) / 4, 256, 0, stream>>>(offs, srcA, dis, pin, mask, hard, alpha, ft, out, N);
}